// Round 1
// baseline (1155.023 us; speedup 1.0000x reference)
//
#include <hip/hip_runtime.h>
#include <hip/hip_bf16.h>

// Problem constants
#define BB 2
#define LL 2048
#define DD 1024
#define HH 16
#define FD 16
#define HD 64
#define EPS 1e-5f

// ---------------------------------------------------------------------------
// Generic fp32 tiled GEMM: C[M,N] = A[M,K] @ B[K,N], row-major.
// 64x64 tile, K-step 16, 256 threads, each thread computes 4x4 outputs.
// Requires M%64==0, N%64==0, K%16==0 (true for all shapes here).
// ---------------------------------------------------------------------------
__global__ __launch_bounds__(256) void gemm_f32(
    const float* __restrict__ A, const float* __restrict__ B,
    float* __restrict__ C, int M, int N, int K) {
  __shared__ float As[16][68];  // [k][m], padded to 68 for conflict-free stores + aligned float4 reads
  __shared__ float Bs[16][64];  // [k][n]
  const int tid = threadIdx.x;
  const int m0 = blockIdx.y * 64, n0 = blockIdx.x * 64;
  const int tm = (tid >> 4) * 4;   // 0..60
  const int tn = (tid & 15) * 4;   // 0..60

  float acc[4][4] = {};

  for (int k0 = 0; k0 < K; k0 += 16) {
    __syncthreads();
    {
      // A tile: 64 rows x 16 cols; one float4 per thread
      int r = tid >> 2, c = (tid & 3) * 4;
      float4 a = *(const float4*)(A + (size_t)(m0 + r) * K + k0 + c);
      As[c + 0][r] = a.x;
      As[c + 1][r] = a.y;
      As[c + 2][r] = a.z;
      As[c + 3][r] = a.w;
    }
    {
      // B tile: 16 rows x 64 cols; one float4 per thread
      int r = tid >> 4, c = (tid & 15) * 4;
      float4 bv = *(const float4*)(B + (size_t)(k0 + r) * N + n0 + c);
      *(float4*)&Bs[r][c] = bv;
    }
    __syncthreads();
#pragma unroll
    for (int kk = 0; kk < 16; kk++) {
      float4 a4 = *(const float4*)&As[kk][tm];
      float4 b4 = *(const float4*)&Bs[kk][tn];
      float av[4] = {a4.x, a4.y, a4.z, a4.w};
      float bv[4] = {b4.x, b4.y, b4.z, b4.w};
#pragma unroll
      for (int i = 0; i < 4; i++)
#pragma unroll
        for (int j = 0; j < 4; j++) acc[i][j] += av[i] * bv[j];
    }
  }

#pragma unroll
  for (int i = 0; i < 4; i++) {
    float* cp = C + (size_t)(m0 + tm + i) * N + n0 + tn;
    *(float4*)cp = make_float4(acc[i][0], acc[i][1], acc[i][2], acc[i][3]);
  }
}

// ---------------------------------------------------------------------------
// Causal quadratic ("rebased") attention.
// Q,K stored as [B*L, H*FD] (projection output), V as [B*L, H*HD].
// O written as [B*L, H*HD] (merged-head layout, pre-divided by z+eps).
// Grid: (L/64, B*H). Block: 256 threads.
// Thread t: query qi = t>>2 (0..63), dim-group dg = t&3 (owns v dims dg*16..+15).
// Each of the 4 threads per query redundantly computes s and z (no reduction).
// ---------------------------------------------------------------------------
__global__ __launch_bounds__(256) void attn_quad(
    const float* __restrict__ Q, const float* __restrict__ K,
    const float* __restrict__ V, float* __restrict__ O) {
  const int bh = blockIdx.y;
  const int b = bh >> 4, h = bh & 15;
  const int q0 = blockIdx.x * 64;
  const int tid = threadIdx.x;
  const int qi = tid >> 2;   // 0..63
  const int dg = tid & 3;    // 0..3

  __shared__ float sK[64][17];   // padded: conflict-free broadcast reads
  __shared__ float sV[64][68];   // padded by 4: 16B-aligned float4, conflict-light

  // Load this thread's query into registers, folding in the FD^-0.5 scale.
  float qreg[16];
  {
    const float* qp = Q + ((size_t)(b * LL + q0 + qi) * (HH * FD)) + h * FD;
#pragma unroll
    for (int f = 0; f < 16; f++) qreg[f] = qp[f] * 0.25f;  // 16^-0.5
  }

  float acc[16] = {};
  float z = 0.0f;

  const int ktiles = (q0 >> 6) + 1;
  for (int kt = 0; kt < ktiles; kt++) {
    const int k0 = kt * 64;
    __syncthreads();
    {
      // K tile: 64x16, one float4 per thread
      int r = tid >> 2, c = (tid & 3) * 4;
      float4 kv = *(const float4*)(K + ((size_t)(b * LL + k0 + r) * (HH * FD)) + h * FD + c);
      sK[r][c + 0] = kv.x;
      sK[r][c + 1] = kv.y;
      sK[r][c + 2] = kv.z;
      sK[r][c + 3] = kv.w;
    }
    {
      // V tile: 64x64, four float4 per thread
      int r = tid >> 2, c0 = (tid & 3) * 16;
      const float* vp = V + ((size_t)(b * LL + k0 + r) * (HH * HD)) + h * HD + c0;
#pragma unroll
      for (int i = 0; i < 4; i++) {
        *(float4*)&sV[r][c0 + i * 4] = *(const float4*)(vp + i * 4);
      }
    }
    __syncthreads();

    // keys j valid while k0 + j <= q0 + qi
    int jmax = q0 + qi - k0 + 1;
    if (jmax > 64) jmax = 64;
    for (int j = 0; j < jmax; j++) {
      float s = 0.0f;
#pragma unroll
      for (int f = 0; f < 16; f++) s += qreg[f] * sK[j][f];
      s = s * s;
      z += s;
      const float* vrow = &sV[j][dg * 16];
#pragma unroll
      for (int d = 0; d < 16; d++) acc[d] += s * vrow[d];
    }
  }

  const float rz = 1.0f / (z + EPS);
  float* op = O + ((size_t)(b * LL + q0 + qi) * (HH * HD)) + h * HD + dg * 16;
#pragma unroll
  for (int d = 0; d < 16; d++) op[d] = acc[d] * rz;
}

// ---------------------------------------------------------------------------
// Launch
// ---------------------------------------------------------------------------
extern "C" void kernel_launch(void* const* d_in, const int* in_sizes, int n_in,
                              void* d_out, int out_size, void* d_ws, size_t ws_size,
                              hipStream_t stream) {
  const float* hs = (const float*)d_in[0];  // [B*L, D] = [4096, 1024]
  const float* Wq = (const float*)d_in[1];  // [1024, 256]
  const float* Wk = (const float*)d_in[2];  // [1024, 256]
  const float* Wv = (const float*)d_in[3];  // [1024, 1024]
  const float* Wo = (const float*)d_in[4];  // [1024, 1024]
  float* out = (float*)d_out;               // [4096, 1024]

  float* ws = (float*)d_ws;
  float* Qb = ws;                 // 4096*256  = 1,048,576 floats
  float* Kb = ws + 1048576;       // 4096*256
  float* Vb = ws + 2097152;       // 4096*1024 = 4,194,304
  float* Ob = ws + 6291456;       // 4096*1024
  // total: 10,485,760 floats = 40 MiB of d_ws

  const int M = BB * LL;  // 4096
  // Projections
  gemm_f32<<<dim3((HH * FD) / 64, M / 64), 256, 0, stream>>>(hs, Wq, Qb, M, HH * FD, DD);
  gemm_f32<<<dim3((HH * FD) / 64, M / 64), 256, 0, stream>>>(hs, Wk, Kb, M, HH * FD, DD);
  gemm_f32<<<dim3((HH * HD) / 64, M / 64), 256, 0, stream>>>(hs, Wv, Vb, M, HH * HD, DD);

  // Attention
  attn_quad<<<dim3(LL / 64, BB * HH), 256, 0, stream>>>(Qb, Kb, Vb, Ob);

  // Output projection
  gemm_f32<<<dim3(DD / 64, M / 64), 256, 0, stream>>>(Ob, Wo, out, M, DD, DD);
}

// Round 2
// 501.814 us; speedup vs baseline: 2.3017x; 2.3017x over previous
//
#include <hip/hip_runtime.h>
#include <hip/hip_bf16.h>

// Problem constants
#define BB 2
#define LL 2048
#define DD 1024
#define HH 16
#define FD 16
#define HD 64
#define EPS 1e-5f

typedef __attribute__((ext_vector_type(4))) float f32x4;
typedef __attribute__((ext_vector_type(8))) short s16x8;

static __device__ __forceinline__ ushort f2bf(float f) {
  __hip_bfloat16 h = __float2bfloat16(f);
  ushort s;
  __builtin_memcpy(&s, &h, 2);
  return s;
}

// ---------------------------------------------------------------------------
// fp32 tiled GEMM: C[M,N] = A[M,K] @ B[K,N] (fp32 out). 64x64 tile, 4x4/thread.
// ---------------------------------------------------------------------------
__global__ __launch_bounds__(256) void gemm_f32(
    const float* __restrict__ A, const float* __restrict__ B,
    float* __restrict__ C, int M, int N, int K) {
  __shared__ float As[16][68];
  __shared__ float Bs[16][64];
  const int tid = threadIdx.x;
  const int m0 = blockIdx.y * 64, n0 = blockIdx.x * 64;
  const int tm = (tid >> 4) * 4;
  const int tn = (tid & 15) * 4;

  float acc[4][4] = {};

  for (int k0 = 0; k0 < K; k0 += 16) {
    __syncthreads();
    {
      int r = tid >> 2, c = (tid & 3) * 4;
      float4 a = *(const float4*)(A + (size_t)(m0 + r) * K + k0 + c);
      As[c + 0][r] = a.x; As[c + 1][r] = a.y; As[c + 2][r] = a.z; As[c + 3][r] = a.w;
    }
    {
      int r = tid >> 4, c = (tid & 15) * 4;
      *(float4*)&Bs[r][c] = *(const float4*)(B + (size_t)(k0 + r) * N + n0 + c);
    }
    __syncthreads();
#pragma unroll
    for (int kk = 0; kk < 16; kk++) {
      float4 a4 = *(const float4*)&As[kk][tm];
      float4 b4 = *(const float4*)&Bs[kk][tn];
      float av[4] = {a4.x, a4.y, a4.z, a4.w};
      float bv[4] = {b4.x, b4.y, b4.z, b4.w};
#pragma unroll
      for (int i = 0; i < 4; i++)
#pragma unroll
        for (int j = 0; j < 4; j++) acc[i][j] += av[i] * bv[j];
    }
  }

#pragma unroll
  for (int i = 0; i < 4; i++) {
    float* cp = C + (size_t)(m0 + tm + i) * N + n0 + tn;
    *(float4*)cp = make_float4(acc[i][0], acc[i][1], acc[i][2], acc[i][3]);
  }
}

// ---------------------------------------------------------------------------
// Same GEMM but bf16 output with a scale (for Q/K/V projections).
// ---------------------------------------------------------------------------
__global__ __launch_bounds__(256) void gemm_f32_bf16out(
    const float* __restrict__ A, const float* __restrict__ B,
    ushort* __restrict__ C, int M, int N, int K, float scale) {
  __shared__ float As[16][68];
  __shared__ float Bs[16][64];
  const int tid = threadIdx.x;
  const int m0 = blockIdx.y * 64, n0 = blockIdx.x * 64;
  const int tm = (tid >> 4) * 4;
  const int tn = (tid & 15) * 4;

  float acc[4][4] = {};

  for (int k0 = 0; k0 < K; k0 += 16) {
    __syncthreads();
    {
      int r = tid >> 2, c = (tid & 3) * 4;
      float4 a = *(const float4*)(A + (size_t)(m0 + r) * K + k0 + c);
      As[c + 0][r] = a.x; As[c + 1][r] = a.y; As[c + 2][r] = a.z; As[c + 3][r] = a.w;
    }
    {
      int r = tid >> 4, c = (tid & 15) * 4;
      *(float4*)&Bs[r][c] = *(const float4*)(B + (size_t)(k0 + r) * N + n0 + c);
    }
    __syncthreads();
#pragma unroll
    for (int kk = 0; kk < 16; kk++) {
      float4 a4 = *(const float4*)&As[kk][tm];
      float4 b4 = *(const float4*)&Bs[kk][tn];
      float av[4] = {a4.x, a4.y, a4.z, a4.w};
      float bv[4] = {b4.x, b4.y, b4.z, b4.w};
#pragma unroll
      for (int i = 0; i < 4; i++)
#pragma unroll
        for (int j = 0; j < 4; j++) acc[i][j] += av[i] * bv[j];
    }
  }

#pragma unroll
  for (int i = 0; i < 4; i++) {
    ushort4 pk;
    pk.x = f2bf(acc[i][0] * scale);
    pk.y = f2bf(acc[i][1] * scale);
    pk.z = f2bf(acc[i][2] * scale);
    pk.w = f2bf(acc[i][3] * scale);
    *(ushort4*)(C + (size_t)(m0 + tm + i) * N + n0 + tn) = pk;
  }
}

// ---------------------------------------------------------------------------
// MFMA causal quadratic attention.
// Q,K: bf16 [B*L, H*16] (Q pre-scaled by 0.25). V: bf16 [B*L, H*64].
// O: fp32 [B*L, H*64], already divided by (z+eps).
// Grid (L/64, B*H), block 256 = 4 waves; wave w owns queries q0+16w..+15.
// Per 64-key tile: S = Q@K^T (4 MFMAs, k-dim 16 padded to 32), square+mask
// in C-layout regs, z partial per lane; S2 -> wave-private LDS (bf16) ->
// A-layout frags; O += S2@V (8 MFMAs). K staged [key][f]; V staged transposed
// [hd][key] so PV B-frags are contiguous b128 reads.
// ---------------------------------------------------------------------------
#define SK_STRIDE 24   // ushorts; 48B rows -> 16B-aligned b128 frag reads
#define SV_STRIDE 72   // ushorts; 144B rows -> 16B-aligned
#define SS_STRIDE 72

__global__ __launch_bounds__(256) void attn_mfma(
    const ushort* __restrict__ Q, const ushort* __restrict__ K,
    const ushort* __restrict__ V, float* __restrict__ O) {
  __shared__ __attribute__((aligned(16))) ushort sK[64 * SK_STRIDE];
  __shared__ __attribute__((aligned(16))) ushort sVt[64 * SV_STRIDE];
  __shared__ __attribute__((aligned(16))) ushort sS2[4 * 16 * SS_STRIDE];

  const int bh = blockIdx.y;
  const int b = bh >> 4, h = bh & 15;
  const int q0 = blockIdx.x * 64;
  const int tid = threadIdx.x;
  const int w = tid >> 6;
  const int lane = tid & 63;
  const int quad = lane >> 4;
  const int l16 = lane & 15;

  // Q A-frag: A[m=l16][k=quad*8+j]; k>=16 is zero padding.
  s16x8 qfrag = {};
  if (quad < 2) {
    const ushort* qp = Q + ((size_t)(b * LL + q0 + w * 16 + l16) * (HH * FD)) + h * FD + quad * 8;
    qfrag = *(const s16x8*)qp;
  }

  f32x4 oacc[4];
#pragma unroll
  for (int nt = 0; nt < 4; nt++) oacc[nt] = (f32x4){0.f, 0.f, 0.f, 0.f};
  float zpart[4] = {0.f, 0.f, 0.f, 0.f};

  ushort* sS2w = sS2 + w * 16 * SS_STRIDE;
  const int gq_base = q0 + w * 16;

  const int ktiles = blockIdx.x + 1;
  for (int kt = 0; kt < ktiles; kt++) {
    const int k0 = kt * 64;
    __syncthreads();
    // stage K tile: 64 keys x 16 f (8B per thread)
    {
      int key = tid >> 2, fg = (tid & 3) * 4;
      const ushort* kp = K + ((size_t)(b * LL + k0 + key) * (HH * FD)) + h * FD + fg;
      *(uint2*)&sK[key * SK_STRIDE + fg] = *(const uint2*)kp;
    }
    // stage V tile transposed: sVt[hd][key] (16 elems per thread)
    {
      int key = tid >> 2, c0 = (tid & 3) * 16;
      const ushort* vp = V + ((size_t)(b * LL + k0 + key) * (HH * HD)) + h * HD + c0;
      ushort tmp[16];
      *(uint4*)&tmp[0] = *(const uint4*)vp;
      *(uint4*)&tmp[8] = *(const uint4*)(vp + 8);
#pragma unroll
      for (int i = 0; i < 16; i++) sVt[(c0 + i) * SV_STRIDE + key] = tmp[i];
    }
    __syncthreads();

    // K B-frags: B[k=f][n=key], lane n=l16 -> key=nt*16+l16, k=quad*8+j (f<16)
    s16x8 kf[4];
#pragma unroll
    for (int nt = 0; nt < 4; nt++) {
      s16x8 f = {};
      if (quad < 2) f = *(const s16x8*)&sK[(nt * 16 + l16) * SK_STRIDE + quad * 8];
      kf[nt] = f;
    }

    // S = Q K^T, square, causal mask, z partial, write S2 strip (bf16)
#pragma unroll
    for (int nt = 0; nt < 4; nt++) {
      f32x4 s = __builtin_amdgcn_mfma_f32_16x16x32_bf16(qfrag, kf[nt], (f32x4){0.f, 0.f, 0.f, 0.f}, 0, 0, 0);
      const int gk = k0 + nt * 16 + l16;
#pragma unroll
      for (int r = 0; r < 4; r++) {
        float v = s[r];
        v = v * v;
        const int gq = gq_base + quad * 4 + r;
        v = (gk <= gq) ? v : 0.0f;
        zpart[r] += v;
        sS2w[(quad * 4 + r) * SS_STRIDE + nt * 16 + l16] = f2bf(v);
      }
    }
    // wave-private LDS round trip: ensure writes complete before frag reads
    __asm__ volatile("s_waitcnt lgkmcnt(0)" ::: "memory");

    // S2 A-frags: A[m=l16][k=key in {quad*8..+7} (+32)]
    s16x8 af0 = *(const s16x8*)&sS2w[l16 * SS_STRIDE + quad * 8];
    s16x8 af1 = *(const s16x8*)&sS2w[l16 * SS_STRIDE + 32 + quad * 8];

    // O += S2 @ V  (V B-frags: B[k=key][n=hd], lane n=l16 -> hd=nt*16+l16)
#pragma unroll
    for (int nt = 0; nt < 4; nt++) {
      s16x8 vf0 = *(const s16x8*)&sVt[(nt * 16 + l16) * SV_STRIDE + quad * 8];
      s16x8 vf1 = *(const s16x8*)&sVt[(nt * 16 + l16) * SV_STRIDE + 32 + quad * 8];
      oacc[nt] = __builtin_amdgcn_mfma_f32_16x16x32_bf16(af0, vf0, oacc[nt], 0, 0, 0);
      oacc[nt] = __builtin_amdgcn_mfma_f32_16x16x32_bf16(af1, vf1, oacc[nt], 0, 0, 0);
    }
  }

  // reduce z across the 16 cols (lanes sharing quad), invert, scale, store
  float rz[4];
#pragma unroll
  for (int r = 0; r < 4; r++) {
    float t = zpart[r];
    t += __shfl_xor(t, 1);
    t += __shfl_xor(t, 2);
    t += __shfl_xor(t, 4);
    t += __shfl_xor(t, 8);
    rz[r] = 1.0f / (t + EPS);
  }
#pragma unroll
  for (int nt = 0; nt < 4; nt++) {
#pragma unroll
    for (int r = 0; r < 4; r++) {
      const int gq = gq_base + quad * 4 + r;
      O[((size_t)(b * LL + gq) * (HH * HD)) + h * HD + nt * 16 + l16] = oacc[nt][r] * rz[r];
    }
  }
}

// ---------------------------------------------------------------------------
// Launch
// ---------------------------------------------------------------------------
extern "C" void kernel_launch(void* const* d_in, const int* in_sizes, int n_in,
                              void* d_out, int out_size, void* d_ws, size_t ws_size,
                              hipStream_t stream) {
  const float* hs = (const float*)d_in[0];  // [4096, 1024]
  const float* Wq = (const float*)d_in[1];  // [1024, 256]
  const float* Wk = (const float*)d_in[2];  // [1024, 256]
  const float* Wv = (const float*)d_in[3];  // [1024, 1024]
  const float* Wo = (const float*)d_in[4];  // [1024, 1024]
  float* out = (float*)d_out;               // [4096, 1024]

  char* ws = (char*)d_ws;
  ushort* Qb = (ushort*)ws;                        // 4096*256*2  = 2 MiB
  ushort* Kb = (ushort*)(ws + (2ull << 20));       // 2 MiB
  ushort* Vb = (ushort*)(ws + (4ull << 20));       // 4096*1024*2 = 8 MiB
  float*  Ob = (float*)(ws + (12ull << 20));       // 4096*1024*4 = 16 MiB

  const int M = BB * LL;  // 4096
  // Projections (bf16 out; Q pre-scaled by FD^-0.5 = 0.25)
  gemm_f32_bf16out<<<dim3((HH * FD) / 64, M / 64), 256, 0, stream>>>(hs, Wq, Qb, M, HH * FD, DD, 0.25f);
  gemm_f32_bf16out<<<dim3((HH * FD) / 64, M / 64), 256, 0, stream>>>(hs, Wk, Kb, M, HH * FD, DD, 1.0f);
  gemm_f32_bf16out<<<dim3((HH * HD) / 64, M / 64), 256, 0, stream>>>(hs, Wv, Vb, M, HH * HD, DD, 1.0f);

  // Attention (MFMA)
  attn_mfma<<<dim3(LL / 64, BB * HH), 256, 0, stream>>>(Qb, Kb, Vb, Ob);

  // Output projection (fp32)
  gemm_f32<<<dim3(DD / 64, M / 64), 256, 0, stream>>>(Ob, Wo, out, M, DD, DD);
}

// Round 5
// 346.166 us; speedup vs baseline: 3.3366x; 1.4496x over previous
//
#include <hip/hip_runtime.h>
#include <hip/hip_bf16.h>

// Problem constants
#define BB 2
#define LL 2048
#define DD 1024
#define HH 16
#define FD 16
#define HD 64
#define EPS 1e-5f
#define RQKV 1536   // fused QKV row stride (256 Q + 256 K + 1024 V)
#define S2SCALE 512.0f  // keeps s^2 in fp16 normal range through the LDS round-trip
#define NFIX 4      // first NFIX positions per (b,h) recomputed in fp32 (low-z rows)

typedef __attribute__((ext_vector_type(4))) float f32x4;
typedef __attribute__((ext_vector_type(8))) _Float16 f16x8;
typedef __attribute__((ext_vector_type(4))) _Float16 f16x4;

// ---------------------------------------------------------------------------
// Transpose + cast: src fp32 [K][N] -> dst fp16 [N][K]. Grid (N/32, K/32).
// ---------------------------------------------------------------------------
__global__ __launch_bounds__(256) void transpose_cast(
    const float* __restrict__ src, _Float16* __restrict__ dst, int K, int N) {
  __shared__ _Float16 s[32][40];
  const int n0 = blockIdx.x * 32, k0 = blockIdx.y * 32;
  const int tid = threadIdx.x;
  {
    int r = tid >> 3, c = (tid & 7) * 4;
    float4 v = *(const float4*)(src + (size_t)(k0 + r) * N + n0 + c);
    f16x4 p = {(_Float16)v.x, (_Float16)v.y, (_Float16)v.z, (_Float16)v.w};
    *(f16x4*)&s[r][c] = p;
  }
  __syncthreads();
  {
    int n = tid >> 3, kk = (tid & 7) * 4;
    f16x4 o = {s[kk + 0][n], s[kk + 1][n], s[kk + 2][n], s[kk + 3][n]};
    *(f16x4*)(dst + (size_t)(n0 + n) * K + k0 + kk) = o;
  }
}

// ---------------------------------------------------------------------------
// MFMA GEMM: C[M,N] = A[M,K] @ Bt[N,K]^T. 128x128 tile, BK=32, 4 waves.
// ---------------------------------------------------------------------------
template <typename AT, typename OutT>
__global__ __launch_bounds__(256) void gemm_tn(
    const AT* __restrict__ A, const _Float16* __restrict__ Bt,
    OutT* __restrict__ C, int M, int N, int K) {
  constexpr int LDT = 40;
  __shared__ __attribute__((aligned(16))) _Float16 sA[128 * LDT];
  __shared__ __attribute__((aligned(16))) _Float16 sB[128 * LDT];
  const int tid = threadIdx.x;
  const int m0 = blockIdx.y * 128, n0 = blockIdx.x * 128;
  const int w = tid >> 6, lane = tid & 63, quad = lane >> 4, l16 = lane & 15;
  const int wm = (w >> 1) * 64, wn = (w & 1) * 64;

  const int sr = tid >> 1, sh = (tid & 1) * 16;
  const AT* Ag = A + (size_t)(m0 + sr) * K + sh;
  const _Float16* Bg = Bt + (size_t)(n0 + sr) * K + sh;
  _Float16* sAw = &sA[sr * LDT + sh];
  _Float16* sBw = &sB[sr * LDT + sh];

  f32x4 acc[4][4];
#pragma unroll
  for (int i = 0; i < 4; i++)
#pragma unroll
    for (int j = 0; j < 4; j++) acc[i][j] = (f32x4){0.f, 0.f, 0.f, 0.f};

  for (int k0 = 0; k0 < K; k0 += 32) {
    __syncthreads();
    if constexpr (sizeof(AT) == 4) {
      float4 a0 = *(const float4*)(Ag + k0);
      float4 a1 = *(const float4*)(Ag + k0 + 4);
      float4 a2 = *(const float4*)(Ag + k0 + 8);
      float4 a3 = *(const float4*)(Ag + k0 + 12);
      f16x8 p0 = {(_Float16)a0.x, (_Float16)a0.y, (_Float16)a0.z, (_Float16)a0.w,
                  (_Float16)a1.x, (_Float16)a1.y, (_Float16)a1.z, (_Float16)a1.w};
      f16x8 p1 = {(_Float16)a2.x, (_Float16)a2.y, (_Float16)a2.z, (_Float16)a2.w,
                  (_Float16)a3.x, (_Float16)a3.y, (_Float16)a3.z, (_Float16)a3.w};
      *(f16x8*)sAw = p0;
      *(f16x8*)(sAw + 8) = p1;
    } else {
      *(f16x8*)sAw = *(const f16x8*)(Ag + k0);
      *(f16x8*)(sAw + 8) = *(const f16x8*)(Ag + k0 + 8);
    }
    *(f16x8*)sBw = *(const f16x8*)(Bg + k0);
    *(f16x8*)(sBw + 8) = *(const f16x8*)(Bg + k0 + 8);
    __syncthreads();

    f16x8 af[4], bf[4];
#pragma unroll
    for (int i = 0; i < 4; i++)
      af[i] = *(const f16x8*)&sA[(wm + i * 16 + l16) * LDT + quad * 8];
#pragma unroll
    for (int j = 0; j < 4; j++)
      bf[j] = *(const f16x8*)&sB[(wn + j * 16 + l16) * LDT + quad * 8];
#pragma unroll
    for (int i = 0; i < 4; i++)
#pragma unroll
      for (int j = 0; j < 4; j++)
        acc[i][j] = __builtin_amdgcn_mfma_f32_16x16x32_f16(af[i], bf[j], acc[i][j], 0, 0, 0);
  }

#pragma unroll
  for (int i = 0; i < 4; i++)
#pragma unroll
    for (int j = 0; j < 4; j++)
#pragma unroll
      for (int r = 0; r < 4; r++) {
        const int row = m0 + wm + i * 16 + quad * 4 + r;
        const int col = n0 + wn + j * 16 + l16;
        C[(size_t)row * N + col] = (OutT)acc[i][j][r];
      }
}

// ---------------------------------------------------------------------------
// MFMA causal quadratic attention (fp16, S2 scaled by 512).
// QKV: fp16 [B*L,1536] fused. O: fp16 [B*L,1024], divided by (z+eps).
// ---------------------------------------------------------------------------
#define SK_STRIDE 24
#define SV_STRIDE 72
#define SS_STRIDE 72

__global__ __launch_bounds__(256) void attn_mfma(
    const _Float16* __restrict__ QKV, _Float16* __restrict__ O) {
  __shared__ __attribute__((aligned(16))) _Float16 sK[64 * SK_STRIDE];
  __shared__ __attribute__((aligned(16))) _Float16 sVt[64 * SV_STRIDE];
  __shared__ __attribute__((aligned(16))) _Float16 sS2[4 * 16 * SS_STRIDE];

  const int bh = blockIdx.y;
  const int b = bh >> 4, h = bh & 15;
  const int q0 = blockIdx.x * 64;
  const int tid = threadIdx.x;
  const int w = tid >> 6;
  const int lane = tid & 63;
  const int quad = lane >> 4;
  const int l16 = lane & 15;

  f16x8 qfrag = {};
  if (quad < 2) {
    const _Float16* qp =
        QKV + (size_t)(b * LL + q0 + w * 16 + l16) * RQKV + h * FD + quad * 8;
    qfrag = *(const f16x8*)qp;
  }

  f32x4 oacc[4];
#pragma unroll
  for (int nt = 0; nt < 4; nt++) oacc[nt] = (f32x4){0.f, 0.f, 0.f, 0.f};
  float zpart[4] = {0.f, 0.f, 0.f, 0.f};

  _Float16* sS2w = sS2 + w * 16 * SS_STRIDE;
  const int gq_base = q0 + w * 16;

  const int ktiles = blockIdx.x + 1;
  for (int kt = 0; kt < ktiles; kt++) {
    const int k0 = kt * 64;
    __syncthreads();
    {
      int key = tid >> 2, fg = (tid & 3) * 4;
      const _Float16* kp =
          QKV + (size_t)(b * LL + k0 + key) * RQKV + 256 + h * FD + fg;
      *(uint2*)&sK[key * SK_STRIDE + fg] = *(const uint2*)kp;
    }
    {
      int key = tid >> 2, c0 = (tid & 3) * 16;
      const _Float16* vp =
          QKV + (size_t)(b * LL + k0 + key) * RQKV + 512 + h * HD + c0;
      _Float16 tmp[16];
      *(f16x8*)&tmp[0] = *(const f16x8*)vp;
      *(f16x8*)&tmp[8] = *(const f16x8*)(vp + 8);
#pragma unroll
      for (int i = 0; i < 16; i++) sVt[(c0 + i) * SV_STRIDE + key] = tmp[i];
    }
    __syncthreads();

    f16x8 kf[4];
#pragma unroll
    for (int nt = 0; nt < 4; nt++) {
      f16x8 f = {};
      if (quad < 2) f = *(const f16x8*)&sK[(nt * 16 + l16) * SK_STRIDE + quad * 8];
      kf[nt] = f;
    }

#pragma unroll
    for (int nt = 0; nt < 4; nt++) {
      f32x4 s = __builtin_amdgcn_mfma_f32_16x16x32_f16(
          qfrag, kf[nt], (f32x4){0.f, 0.f, 0.f, 0.f}, 0, 0, 0);
      const int gk = k0 + nt * 16 + l16;
#pragma unroll
      for (int r = 0; r < 4; r++) {
        float sv = s[r] * 0.0625f;
        sv = sv * sv * S2SCALE;
        const int gq = gq_base + quad * 4 + r;
        sv = (gk <= gq) ? sv : 0.0f;
        zpart[r] += sv;
        sS2w[(quad * 4 + r) * SS_STRIDE + nt * 16 + l16] = (_Float16)sv;
      }
    }
    __asm__ volatile("s_waitcnt lgkmcnt(0)" ::: "memory");

    f16x8 af0 = *(const f16x8*)&sS2w[l16 * SS_STRIDE + quad * 8];
    f16x8 af1 = *(const f16x8*)&sS2w[l16 * SS_STRIDE + 32 + quad * 8];

#pragma unroll
    for (int nt = 0; nt < 4; nt++) {
      f16x8 vf0 = *(const f16x8*)&sVt[(nt * 16 + l16) * SV_STRIDE + quad * 8];
      f16x8 vf1 = *(const f16x8*)&sVt[(nt * 16 + l16) * SV_STRIDE + 32 + quad * 8];
      oacc[nt] = __builtin_amdgcn_mfma_f32_16x16x32_f16(af0, vf0, oacc[nt], 0, 0, 0);
      oacc[nt] = __builtin_amdgcn_mfma_f32_16x16x32_f16(af1, vf1, oacc[nt], 0, 0, 0);
    }
  }

  float rz[4];
#pragma unroll
  for (int r = 0; r < 4; r++) {
    float t = zpart[r];
    t += __shfl_xor(t, 1);
    t += __shfl_xor(t, 2);
    t += __shfl_xor(t, 4);
    t += __shfl_xor(t, 8);
    rz[r] = 1.0f / (t + S2SCALE * EPS);
  }
#pragma unroll
  for (int nt = 0; nt < 4; nt++) {
#pragma unroll
    for (int r = 0; r < 4; r++) {
      const int gq = gq_base + quad * 4 + r;
      O[(size_t)(b * LL + gq) * (HH * HD) + h * HD + nt * 16 + l16] =
          (_Float16)(oacc[nt][r] * rz[r]);
    }
  }
}

// ---------------------------------------------------------------------------
// fp32-exact recompute of the first NFIX positions per (b,h).
// Rationale: for position i, z = sum_{j<=i} s^2 can be O(eps); the ratio
// s^2/(z+eps) is then hyper-sensitive to the ABSOLUTE fp16 rounding of q,k
// (the round-3/4 failure: one low-z row-0, error ~0.14, invariant to S2SCALE).
// Here q,k,v and the ratio are computed from the original fp32 inputs.
// Grid: 32 blocks = (b,h); block 256.
// ---------------------------------------------------------------------------
__global__ __launch_bounds__(256) void fix_early(
    const float* __restrict__ hs, const float* __restrict__ Wq,
    const float* __restrict__ Wk, const float* __restrict__ Wv,
    _Float16* __restrict__ Oatt) {
  const int b = blockIdx.x >> 4, h = blockIdx.x & 15;
  __shared__ float sHS[NFIX][DD];
  __shared__ float sQ[NFIX][16], sKs[NFIX][16], sV[NFIX][64];
  const int tid = threadIdx.x;

  for (int i = tid; i < NFIX * DD / 4; i += 256) {
    int p = i / (DD / 4), c = (i % (DD / 4)) * 4;
    *(float4*)&sHS[p][c] = *(const float4*)(hs + (size_t)(b * LL + p) * DD + c);
  }
  __syncthreads();

  // NFIX*96 projection dots of length 1024
  for (int t = tid; t < NFIX * 96; t += 256) {
    int p = t / 96, r = t % 96;
    const float* W;
    int col, ncol;
    if (r < 16) { W = Wq; col = h * 16 + r; ncol = 256; }
    else if (r < 32) { W = Wk; col = h * 16 + (r - 16); ncol = 256; }
    else { W = Wv; col = h * 64 + (r - 32); ncol = 1024; }
    float acc = 0.f;
    for (int d = 0; d < DD; d++) acc += sHS[p][d] * W[(size_t)d * ncol + col];
    if (r < 16) sQ[p][r] = acc;
    else if (r < 32) sKs[p][r - 16] = acc;
    else sV[p][r - 32] = acc;
  }
  __syncthreads();

  // o_p[d] for p<NFIX, d<64 : NFIX*64 = 256 outputs, one per thread
  {
    int p = tid >> 6, d = tid & 63;
    float num = 0.f, z = 0.f;
    for (int j = 0; j <= p; j++) {
      float s = 0.f;
#pragma unroll
      for (int f = 0; f < 16; f++) s += sQ[p][f] * sKs[j][f];
      s *= 0.25f;  // FD^-0.5 applied to q
      s = s * s;
      z += s;
      num += s * sV[j][d];
    }
    Oatt[(size_t)(b * LL + p) * (HH * HD) + h * HD + d] =
        (_Float16)(num / (z + EPS));
  }
}

// ---------------------------------------------------------------------------
// Launch
// ---------------------------------------------------------------------------
extern "C" void kernel_launch(void* const* d_in, const int* in_sizes, int n_in,
                              void* d_out, int out_size, void* d_ws, size_t ws_size,
                              hipStream_t stream) {
  const float* hs = (const float*)d_in[0];  // [4096, 1024]
  const float* Wq = (const float*)d_in[1];  // [1024, 256]
  const float* Wk = (const float*)d_in[2];  // [1024, 256]
  const float* Wv = (const float*)d_in[3];  // [1024, 1024]
  const float* Wo = (const float*)d_in[4];  // [1024, 1024]
  float* out = (float*)d_out;               // [4096, 1024]

  char* ws = (char*)d_ws;
  _Float16* WqkvT = (_Float16*)ws;                    // [1536][1024] = 3 MiB
  _Float16* WoT   = (_Float16*)(ws + (3ull << 20));   // [1024][1024] = 2 MiB
  _Float16* QKV   = (_Float16*)(ws + (8ull << 20));   // [4096][1536] = 12 MiB
  _Float16* Oatt  = (_Float16*)(ws + (20ull << 20));  // [4096][1024] = 8 MiB

  const int M = BB * LL;  // 4096

  transpose_cast<<<dim3(256 / 32, DD / 32), 256, 0, stream>>>(Wq, WqkvT, DD, 256);
  transpose_cast<<<dim3(256 / 32, DD / 32), 256, 0, stream>>>(Wk, WqkvT + 256 * DD, DD, 256);
  transpose_cast<<<dim3(DD / 32, DD / 32), 256, 0, stream>>>(Wv, WqkvT + 512 * DD, DD, DD);
  transpose_cast<<<dim3(DD / 32, DD / 32), 256, 0, stream>>>(Wo, WoT, DD, DD);

  gemm_tn<float, _Float16><<<dim3(RQKV / 128, M / 128), 256, 0, stream>>>(
      hs, WqkvT, QKV, M, RQKV, DD);

  attn_mfma<<<dim3(LL / 64, BB * HH), 256, 0, stream>>>(QKV, Oatt);

  // fp32-exact first NFIX positions per (b,h) (overwrites low-z rows)
  fix_early<<<dim3(BB * HH), 256, 0, stream>>>(hs, Wq, Wk, Wv, Oatt);

  gemm_tn<_Float16, float><<<dim3(DD / 128, M / 128), 256, 0, stream>>>(
      Oatt, WoT, out, M, DD, DD);
}